// Round 8
// baseline (207.634 us; speedup 1.0000x reference)
//
#include <hip/hip_runtime.h>

// MACE symmetric contraction, B=4096 nodes, C=256 channels, I=16.
//
// Per (b,c):  s[b,c] = sum_p x_p * t[b,p],
//   t[b,p] = sum_{k<256} U3w[c,p,q,i]*x_q*x_i   (k=q*16+i)
//          + sum_q c2[c,p,q]*x_q (k=256+q)  +  c1[c,p] (k=272)
// => K=273 (pad 288=9*32) matmul on mfma_f32_16x16x32_bf16.
// A = coeff[p,k] (regs, static per wave), B = y[k,node] built per tile.
//
// R8: wave-autonomous contract — NO LDS, NO __syncthreads. R6/R7 showed the
// block-wide stage barrier (vmcnt(0) drain) leaves all pipes <25% busy at a
// constant ~67 us regardless of inner structure. Wave w only reads channel
// c0+w's 64B slice per node, so x goes global->register directly (4 dwordx4
// per tile; g-lanes share addresses -> broadcast; 16 full 64B segments per
// instr). Register double-buffer, 1-tile-ahead prefetch, 8-tile unrolled.
// NOTE: ~114 us of total dur_us is fixed (harness + precompute + linear).

#define B_NODES 4096
#define C_CH    256
#define K3      23
#define K2      4

#define KSTEPS   9
#define KB_ELEMS (KSTEPS * 64 * 8)   // 4608 bf16 per channel
#define KB_U32   (KB_ELEMS / 2)      // 2304 u32 per channel

#define TILES_PER_WAVE 8             // 128 nodes per wave

typedef short  short8 __attribute__((ext_vector_type(8)));
typedef float  f32x4  __attribute__((ext_vector_type(4)));

// ws layout (bytes): [bfrag: C*4608*2][sT: C*B*4]
static constexpr size_t OFF_BF_BYTES = 0;
static constexpr size_t OFF_ST_BYTES = (size_t)C_CH * KB_ELEMS * 2;

__device__ inline unsigned short f2bf_rne(float f) {
  union { float f; unsigned u; } v; v.f = f;
  unsigned r = v.u + 0x7FFFu + ((v.u >> 16) & 1u);
  return (unsigned short)(r >> 16);
}
__device__ inline unsigned fbits(float f) {
  union { float f; unsigned u; } v; v.f = f; return v.u;
}

// ---------------------------------------------------------------------------
// Kernel 1: coeff in fragment order (lane&15 = p, k = s*32+(lane>>4)*8+j).
// grid (9 steps, 32 channel-groups of 8); steps 0..7 stage a 47 KB U3 slice.
// ---------------------------------------------------------------------------
__global__ __launch_bounds__(256) void precompute_bfrag(
    const float* __restrict__ U3, const float* __restrict__ U2,
    const float* __restrict__ U1, const float* __restrict__ w3,
    const float* __restrict__ w2, const float* __restrict__ w1,
    unsigned int* __restrict__ bfrag_u32) {
  const int s  = blockIdx.x;        // K-step 0..8
  const int c0 = blockIdx.y * 8;    // 8 channels per block
  const int t  = threadIdx.x;
  const int lane = t >> 2;          // fragment lane
  const int jj   = (t & 3) * 2;     // 0,2,4,6
  const int p = lane & 15, g = lane >> 4;

  __shared__ float su3[512 * 23];   // rows: p*32 + qb*16 + i

  if (s < 8) {
    for (int l = t; l < 512 * 23; l += 256) {
      const int row = l / 23, col = l - row * 23;
      const int pp = row >> 5, qb = (row >> 4) & 1, ii = row & 15;
      su3[l] = U3[(size_t)((pp * 16 + (2 * s + qb)) * 16 + ii) * K3 + col];
    }
    __syncthreads();

    const int r0 = p * 32 + (g >> 1) * 16 + (g & 1) * 8 + jj;
    float u0[K3], u1[K3];
#pragma unroll
    for (int k3 = 0; k3 < K3; ++k3) {
      u0[k3] = su3[(size_t)r0 * K3 + k3];
      u1[k3] = su3[(size_t)(r0 + 1) * K3 + k3];
    }
#pragma unroll
    for (int ch = 0; ch < 8; ++ch) {
      const int c = c0 + ch;
      float a0 = 0.f, a1 = 0.f;
#pragma unroll
      for (int k3 = 0; k3 < K3; ++k3) {
        const float wv = w3[c * K3 + k3];   // uniform -> scalar load
        a0 += u0[k3] * wv;
        a1 += u1[k3] * wv;
      }
      bfrag_u32[(size_t)c * KB_U32 + s * 256 + t] =
          (unsigned)f2bf_rne(a0) | ((unsigned)f2bf_rne(a1) << 16);
    }
  } else {
    // s == 8: linear rows (x_q), constant row (k==272), pad 0.
#pragma unroll
    for (int ch = 0; ch < 8; ++ch) {
      const int c = c0 + ch;
      float v[2] = {0.f, 0.f};
#pragma unroll
      for (int e = 0; e < 2; ++e) {
        const int k = 256 + g * 8 + jj + e;
        if (k < 272) {
          const int q = k - 256;
          float a = 0.f;
#pragma unroll
          for (int k2 = 0; k2 < K2; ++k2)
            a += U2[(size_t)(p * 16 + q) * K2 + k2] * w2[c * K2 + k2];
          v[e] = a;
        } else if (k == 272) {
          v[e] = U1[p] * w1[c];
        }
      }
      bfrag_u32[(size_t)c * KB_U32 + s * 256 + t] =
          (unsigned)f2bf_rne(v[0]) | ((unsigned)f2bf_rne(v[1]) << 16);
    }
  }
}

// ---------------------------------------------------------------------------
// Kernel 2: wave-autonomous MFMA contraction. Block = 256 thr (4 waves);
// wave w owns channel c0+w; each wave covers 128 nodes (8 tiles of 16).
// No LDS, no barriers. x loaded global->reg per tile, 1-ahead prefetch.
// ---------------------------------------------------------------------------
__global__ __launch_bounds__(256)
__attribute__((amdgpu_waves_per_eu(2, 4)))
void contract_mfma(
    const float* __restrict__ x, const short8* __restrict__ bfragv,
    float* __restrict__ sT) {
  const int c0  = blockIdx.x * 4;                    // channel group (fastest)
  const int nb0 = blockIdx.y * (TILES_PER_WAVE * 16);
  const int t   = threadIdx.x;
  const int w = t >> 6, lane = t & 63, n = lane & 15, g = lane >> 4;
  const int ch = c0 + w;

  // Coeff fragments for this wave's channel: 9 coalesced dwordx4 -> 36 VGPRs.
  short8 bf[KSTEPS];
  {
    const short8* bp = bfragv + (size_t)ch * (KSTEPS * 64);
#pragma unroll
    for (int s = 0; s < KSTEPS; ++s) bf[s] = bp[s * 64 + lane];
  }

  const bool ghi = (g & 1) != 0;        // i-half: i = (g&1)*8 + j
  const bool gq  = ((g >> 1) & 1) != 0; // q = 2s + (g>>1)
  float* sTrow = sT + (size_t)ch * B_NODES + nb0;

  // x address for lane's node in tile T: (nb0+T*16+n) row, this wave's 64B.
  const float* xb = x + (size_t)(nb0 + n) * (C_CH * 16) + (size_t)ch * 16;
  const size_t tstride = (size_t)16 * C_CH * 16;     // 16 nodes

  float4 bufA[4], bufB[4];
  {
    const float4* p = (const float4*)xb;
    bufA[0] = p[0]; bufA[1] = p[1]; bufA[2] = p[2]; bufA[3] = p[3];
  }

#pragma unroll
  for (int T = 0; T < TILES_PER_WAVE; ++T) {
    // Prefetch next tile into the other buffer (independent regs).
    if (T + 1 < TILES_PER_WAVE) {
      const float4* p = (const float4*)(xb + (size_t)(T + 1) * tstride);
      float4* nb = (T & 1) ? bufA : bufB;
      nb[0] = p[0]; nb[1] = p[1]; nb[2] = p[2]; nb[3] = p[3];
    }
    const float4* cb = (T & 1) ? bufB : bufA;
    float xr[16];
#pragma unroll
    for (int v4 = 0; v4 < 4; ++v4) {
      xr[v4 * 4 + 0] = cb[v4].x; xr[v4 * 4 + 1] = cb[v4].y;
      xr[v4 * 4 + 2] = cb[v4].z; xr[v4 * 4 + 3] = cb[v4].w;
    }
    float xh[8], xq[8];
#pragma unroll
    for (int j = 0; j < 8; ++j) xh[j] = ghi ? xr[8 + j] : xr[j];
#pragma unroll
    for (int s = 0; s < 8; ++s) xq[s] = gq ? xr[2 * s + 1] : xr[2 * s];

    f32x4 acc = (f32x4){0.f, 0.f, 0.f, 0.f};

    // Steps 0..7: quadratic rows y[k] = x_q * x_i.
#pragma unroll
    for (int s = 0; s < 8; ++s) {
      union { unsigned u[4]; short8 v; } af;
#pragma unroll
      for (int m2 = 0; m2 < 4; ++m2) {
        const float y0 = xq[s] * xh[m2 * 2];
        const float y1 = xq[s] * xh[m2 * 2 + 1];
        af.u[m2] = __builtin_amdgcn_perm(fbits(y1), fbits(y0), 0x07060302u);
      }
      acc = __builtin_amdgcn_mfma_f32_16x16x32_bf16(bf[s], af.v, acc, 0, 0, 0);
    }
    // Step 8: linear rows (g<2 -> x half, matches ghi), const-1 (g==2,j==0).
    {
      union { unsigned u[4]; short8 v; } af;
#pragma unroll
      for (int m2 = 0; m2 < 4; ++m2) {
        float y0 = (g < 2) ? xh[m2 * 2]     : 0.f;
        float y1 = (g < 2) ? xh[m2 * 2 + 1] : 0.f;
        if (m2 == 0) y0 = (g == 2) ? 1.0f : y0;
        af.u[m2] = __builtin_amdgcn_perm(fbits(y1), fbits(y0), 0x07060302u);
      }
      acc = __builtin_amdgcn_mfma_f32_16x16x32_bf16(bf[8], af.v, acc, 0, 0, 0);
    }

    // Epilogue. D[row p = g*4+r][col node = n]; lane's xr IS its node's row:
    //   s[node] = sum_r t[g*4+r] * xr[g*4+r], then butterfly over g.
    float xsel[4];
#pragma unroll
    for (int r = 0; r < 4; ++r) {
      const float lo = (g & 2) ? xr[8 + r]  : xr[r];
      const float hi = (g & 2) ? xr[12 + r] : xr[4 + r];
      xsel[r] = (g & 1) ? hi : lo;
    }
    float v = acc[0] * xsel[0] + acc[1] * xsel[1] +
              acc[2] * xsel[2] + acc[3] * xsel[3];
    v += __shfl_xor(v, 16);
    v += __shfl_xor(v, 32);
    if (g == 0) sTrow[T * 16 + n] = v;
  }
}

// ---------------------------------------------------------------------------
// Kernel 3: out[b,d] = (1/16) * sum_c sT[c,b] * W[c,d]  (fp32, 64x64 tiles)
// ---------------------------------------------------------------------------
__global__ __launch_bounds__(256) void linear_kernel(
    const float* __restrict__ sT, const float* __restrict__ W,
    float* __restrict__ out) {
  const int b0 = blockIdx.x * 64;
  const int d0 = blockIdx.y * 64;
  const int t  = threadIdx.x;
  const int tx = t & 15;
  const int ty = t >> 4;

  __shared__ float As[16][64];
  __shared__ float Bs[16][64];
  float acc[4][4] = {};

  for (int k0 = 0; k0 < C_CH; k0 += 16) {
    const int kk  = t >> 6;
    const int col = t & 63;
#pragma unroll
    for (int r = 0; r < 4; ++r) {
      As[kk + r * 4][col] = sT[(size_t)(k0 + kk + r * 4) * B_NODES + b0 + col];
      Bs[kk + r * 4][col] = W[(size_t)(k0 + kk + r * 4) * C_CH + d0 + col];
    }
    __syncthreads();
#pragma unroll
    for (int k = 0; k < 16; ++k) {
      float a[4], bv[4];
#pragma unroll
      for (int i = 0; i < 4; ++i) a[i] = As[k][ty * 4 + i];
#pragma unroll
      for (int j = 0; j < 4; ++j) bv[j] = Bs[k][tx * 4 + j];
#pragma unroll
      for (int i = 0; i < 4; ++i)
#pragma unroll
        for (int j = 0; j < 4; ++j) acc[i][j] += a[i] * bv[j];
    }
    __syncthreads();
  }

#pragma unroll
  for (int i = 0; i < 4; ++i) {
    float4 v = make_float4(acc[i][0] * 0.0625f, acc[i][1] * 0.0625f,
                           acc[i][2] * 0.0625f, acc[i][3] * 0.0625f);
    *(float4*)(out + (size_t)(b0 + ty * 4 + i) * C_CH + d0 + tx * 4) = v;
  }
}

extern "C" void kernel_launch(void* const* d_in, const int* in_sizes, int n_in,
                              void* d_out, int out_size, void* d_ws, size_t ws_size,
                              hipStream_t stream) {
  const float* x  = (const float*)d_in[0];
  const float* U3 = (const float*)d_in[1];
  const float* U2 = (const float*)d_in[2];
  const float* U1 = (const float*)d_in[3];
  const float* w3 = (const float*)d_in[4];
  const float* w2 = (const float*)d_in[5];
  const float* w1 = (const float*)d_in[6];
  const float* Wl = (const float*)d_in[7];

  unsigned int* bfrag = (unsigned int*)((char*)d_ws + OFF_BF_BYTES);
  float*        sT    = (float*)((char*)d_ws + OFF_ST_BYTES);
  float*        out   = (float*)d_out;

  precompute_bfrag<<<dim3(KSTEPS, C_CH / 8), dim3(256), 0, stream>>>(
      U3, U2, U1, w3, w2, w1, bfrag);
  contract_mfma<<<dim3(C_CH / 4, B_NODES / (TILES_PER_WAVE * 16)), dim3(256), 0, stream>>>(
      x, (const short8*)bfrag, sT);
  linear_kernel<<<dim3(B_NODES / 64, C_CH / 64), dim3(256), 0, stream>>>(sT, Wl, out);
}

// Round 9
// 193.662 us; speedup vs baseline: 1.0721x; 1.0721x over previous
//
#include <hip/hip_runtime.h>

// MACE symmetric contraction, B=4096 nodes, C=256 channels, I=16.
//
// Per (b,c):  s[b,c] = sum_p x_p * t[b,p],
//   t[b,p] = sum_{k<256} U3w[c,p,q,i]*x_q*x_i   (k=q*16+i)
//          + sum_q c2[c,p,q]*x_q (k=256+q)  +  c1[c,p] (k=272)
// => K=273 (pad 288=9*32) matmul on mfma_f32_16x16x32_bf16.
// A = coeff[p,k] (regs, static per wave), B = y[k,node] built per tile.
//
// R9: R8's wave-autonomous design with the alloca->LDS promotion bug fixed.
// R8's pointer-select double buffer ((T&1)?bufA:bufB) made private arrays
// address-taken -> AMDGPUPromoteAlloca striped them in LDS (16 KB/block,
// 3.1e7 bank-conflict cycles = the whole dispatch). Now: named float4
// registers, manual 2x-unrolled tile loop with compile-time swap, constant
// array indices only. No __shared__, no __syncthreads.
// NOTE: ~114 us of total dur_us is fixed (harness + precompute + linear).

#define B_NODES 4096
#define C_CH    256
#define K3      23
#define K2      4

#define KSTEPS   9
#define KB_ELEMS (KSTEPS * 64 * 8)   // 4608 bf16 per channel
#define KB_U32   (KB_ELEMS / 2)      // 2304 u32 per channel

#define TILES_PER_WAVE 8             // 128 nodes per wave

typedef short  short8 __attribute__((ext_vector_type(8)));
typedef float  f32x4  __attribute__((ext_vector_type(4)));

// ws layout (bytes): [bfrag: C*4608*2][sT: C*B*4]
static constexpr size_t OFF_BF_BYTES = 0;
static constexpr size_t OFF_ST_BYTES = (size_t)C_CH * KB_ELEMS * 2;

__device__ inline unsigned short f2bf_rne(float f) {
  union { float f; unsigned u; } v; v.f = f;
  unsigned r = v.u + 0x7FFFu + ((v.u >> 16) & 1u);
  return (unsigned short)(r >> 16);
}
__device__ inline unsigned fbits(float f) {
  union { float f; unsigned u; } v; v.f = f; return v.u;
}

// ---------------------------------------------------------------------------
// Kernel 1: coeff in fragment order (lane&15 = p, k = s*32+(lane>>4)*8+j).
// grid (9 steps, 32 channel-groups of 8); steps 0..7 stage a 47 KB U3 slice.
// ---------------------------------------------------------------------------
__global__ __launch_bounds__(256) void precompute_bfrag(
    const float* __restrict__ U3, const float* __restrict__ U2,
    const float* __restrict__ U1, const float* __restrict__ w3,
    const float* __restrict__ w2, const float* __restrict__ w1,
    unsigned int* __restrict__ bfrag_u32) {
  const int s  = blockIdx.x;        // K-step 0..8
  const int c0 = blockIdx.y * 8;    // 8 channels per block
  const int t  = threadIdx.x;
  const int lane = t >> 2;          // fragment lane
  const int jj   = (t & 3) * 2;     // 0,2,4,6
  const int p = lane & 15, g = lane >> 4;

  __shared__ float su3[512 * 23];   // rows: p*32 + qb*16 + i

  if (s < 8) {
    for (int l = t; l < 512 * 23; l += 256) {
      const int row = l / 23, col = l - row * 23;
      const int pp = row >> 5, qb = (row >> 4) & 1, ii = row & 15;
      su3[l] = U3[(size_t)((pp * 16 + (2 * s + qb)) * 16 + ii) * K3 + col];
    }
    __syncthreads();

    const int r0 = p * 32 + (g >> 1) * 16 + (g & 1) * 8 + jj;
    float u0[K3], u1[K3];
#pragma unroll
    for (int k3 = 0; k3 < K3; ++k3) {
      u0[k3] = su3[(size_t)r0 * K3 + k3];
      u1[k3] = su3[(size_t)(r0 + 1) * K3 + k3];
    }
#pragma unroll
    for (int ch = 0; ch < 8; ++ch) {
      const int c = c0 + ch;
      float a0 = 0.f, a1 = 0.f;
#pragma unroll
      for (int k3 = 0; k3 < K3; ++k3) {
        const float wv = w3[c * K3 + k3];   // uniform -> scalar load
        a0 += u0[k3] * wv;
        a1 += u1[k3] * wv;
      }
      bfrag_u32[(size_t)c * KB_U32 + s * 256 + t] =
          (unsigned)f2bf_rne(a0) | ((unsigned)f2bf_rne(a1) << 16);
    }
  } else {
    // s == 8: linear rows (x_q), constant row (k==272), pad 0.
#pragma unroll
    for (int ch = 0; ch < 8; ++ch) {
      const int c = c0 + ch;
      float v[2] = {0.f, 0.f};
#pragma unroll
      for (int e = 0; e < 2; ++e) {
        const int k = 256 + g * 8 + jj + e;
        if (k < 272) {
          const int q = k - 256;
          float a = 0.f;
#pragma unroll
          for (int k2 = 0; k2 < K2; ++k2)
            a += U2[(size_t)(p * 16 + q) * K2 + k2] * w2[c * K2 + k2];
          v[e] = a;
        } else if (k == 272) {
          v[e] = U1[p] * w1[c];
        }
      }
      bfrag_u32[(size_t)c * KB_U32 + s * 256 + t] =
          (unsigned)f2bf_rne(v[0]) | ((unsigned)f2bf_rne(v[1]) << 16);
    }
  }
}

// ---------------------------------------------------------------------------
// Kernel 2: wave-autonomous MFMA contraction. Block = 256 thr (4 waves);
// wave w owns channel c0+w; each wave covers 128 nodes (8 tiles of 16).
// No LDS, no barriers. x loaded global->named-registers, 1-ahead prefetch.
// ---------------------------------------------------------------------------

// Full per-tile compute from 4 named float4 regs. Constant indices only.
#define TILE_BODY(X0, X1, X2, X3, Tc)                                          \
  {                                                                            \
    float xr[16];                                                              \
    xr[0] = (X0).x;  xr[1] = (X0).y;  xr[2] = (X0).z;  xr[3] = (X0).w;         \
    xr[4] = (X1).x;  xr[5] = (X1).y;  xr[6] = (X1).z;  xr[7] = (X1).w;         \
    xr[8] = (X2).x;  xr[9] = (X2).y;  xr[10] = (X2).z; xr[11] = (X2).w;        \
    xr[12] = (X3).x; xr[13] = (X3).y; xr[14] = (X3).z; xr[15] = (X3).w;        \
    float xh[8], xq[8];                                                        \
    _Pragma("unroll")                                                          \
    for (int j = 0; j < 8; ++j) xh[j] = ghi ? xr[8 + j] : xr[j];               \
    _Pragma("unroll")                                                          \
    for (int s = 0; s < 8; ++s) xq[s] = gq ? xr[2 * s + 1] : xr[2 * s];        \
    f32x4 acc = (f32x4){0.f, 0.f, 0.f, 0.f};                                   \
    _Pragma("unroll")                                                          \
    for (int s = 0; s < 8; ++s) {                                              \
      union { unsigned u[4]; short8 v; } af;                                   \
      _Pragma("unroll")                                                        \
      for (int m2 = 0; m2 < 4; ++m2) {                                         \
        const float y0 = xq[s] * xh[m2 * 2];                                   \
        const float y1 = xq[s] * xh[m2 * 2 + 1];                               \
        af.u[m2] = __builtin_amdgcn_perm(fbits(y1), fbits(y0), 0x07060302u);   \
      }                                                                        \
      acc = __builtin_amdgcn_mfma_f32_16x16x32_bf16(bf[s], af.v, acc, 0, 0, 0);\
    }                                                                          \
    {                                                                          \
      union { unsigned u[4]; short8 v; } af;                                   \
      _Pragma("unroll")                                                        \
      for (int m2 = 0; m2 < 4; ++m2) {                                         \
        float y0 = (g < 2) ? xh[m2 * 2] : 0.f;                                 \
        float y1 = (g < 2) ? xh[m2 * 2 + 1] : 0.f;                             \
        if (m2 == 0) y0 = (g == 2) ? 1.0f : y0;                                \
        af.u[m2] = __builtin_amdgcn_perm(fbits(y1), fbits(y0), 0x07060302u);   \
      }                                                                        \
      acc = __builtin_amdgcn_mfma_f32_16x16x32_bf16(bf[8], af.v, acc, 0, 0, 0);\
    }                                                                          \
    float xsel[4];                                                             \
    _Pragma("unroll")                                                          \
    for (int r = 0; r < 4; ++r) {                                              \
      const float lo = (g & 2) ? xr[8 + r] : xr[r];                            \
      const float hi = (g & 2) ? xr[12 + r] : xr[4 + r];                       \
      xsel[r] = (g & 1) ? hi : lo;                                             \
    }                                                                          \
    float v = acc[0] * xsel[0] + acc[1] * xsel[1] +                            \
              acc[2] * xsel[2] + acc[3] * xsel[3];                             \
    v += __shfl_xor(v, 16);                                                    \
    v += __shfl_xor(v, 32);                                                    \
    if (g == 0) sTrow[(Tc)*16 + n] = v;                                        \
  }

__global__ __launch_bounds__(256)
__attribute__((amdgpu_waves_per_eu(2, 4)))
void contract_mfma(
    const float* __restrict__ x, const short8* __restrict__ bfragv,
    float* __restrict__ sT) {
  const int c0  = blockIdx.x * 4;                    // channel group (fastest)
  const int nb0 = blockIdx.y * (TILES_PER_WAVE * 16);
  const int t   = threadIdx.x;
  const int w = t >> 6, lane = t & 63, n = lane & 15, g = lane >> 4;
  const int ch = c0 + w;

  // Coeff fragments for this wave's channel: 9 coalesced dwordx4 -> 36 VGPRs.
  short8 bf[KSTEPS];
  {
    const short8* bp = bfragv + (size_t)ch * (KSTEPS * 64);
#pragma unroll
    for (int s = 0; s < KSTEPS; ++s) bf[s] = bp[s * 64 + lane];
  }

  const bool ghi = (g & 1) != 0;        // i-half: i = (g&1)*8 + j
  const bool gq  = ((g >> 1) & 1) != 0; // q = 2s + (g>>1)
  float* sTrow = sT + (size_t)ch * B_NODES + nb0;

  // x address for lane's node in tile T: row (nb0+T*16+n), this wave's 64B.
  const float* xb = x + (size_t)(nb0 + n) * (C_CH * 16) + (size_t)ch * 16;
  const size_t tstride = (size_t)16 * C_CH * 16;     // 16 nodes

  // Named register double-buffer (a*, b*). No address-of -> no alloca.
  float4 a0, a1, a2, a3, b0, b1, b2, b3;
  {
    const float4* p = (const float4*)xb;
    a0 = p[0]; a1 = p[1]; a2 = p[2]; a3 = p[3];
  }

#pragma unroll
  for (int TT = 0; TT < TILES_PER_WAVE / 2; ++TT) {
    {
      const float4* p = (const float4*)(xb + (size_t)(2 * TT + 1) * tstride);
      b0 = p[0]; b1 = p[1]; b2 = p[2]; b3 = p[3];
    }
    TILE_BODY(a0, a1, a2, a3, 2 * TT);
    if (TT + 1 < TILES_PER_WAVE / 2) {
      const float4* p = (const float4*)(xb + (size_t)(2 * TT + 2) * tstride);
      a0 = p[0]; a1 = p[1]; a2 = p[2]; a3 = p[3];
    }
    TILE_BODY(b0, b1, b2, b3, 2 * TT + 1);
  }
}

// ---------------------------------------------------------------------------
// Kernel 3: out[b,d] = (1/16) * sum_c sT[c,b] * W[c,d]  (fp32, 64x64 tiles)
// ---------------------------------------------------------------------------
__global__ __launch_bounds__(256) void linear_kernel(
    const float* __restrict__ sT, const float* __restrict__ W,
    float* __restrict__ out) {
  const int b0 = blockIdx.x * 64;
  const int d0 = blockIdx.y * 64;
  const int t  = threadIdx.x;
  const int tx = t & 15;
  const int ty = t >> 4;

  __shared__ float As[16][64];
  __shared__ float Bs[16][64];
  float acc[4][4] = {};

  for (int k0 = 0; k0 < C_CH; k0 += 16) {
    const int kk  = t >> 6;
    const int col = t & 63;
#pragma unroll
    for (int r = 0; r < 4; ++r) {
      As[kk + r * 4][col] = sT[(size_t)(k0 + kk + r * 4) * B_NODES + b0 + col];
      Bs[kk + r * 4][col] = W[(size_t)(k0 + kk + r * 4) * C_CH + d0 + col];
    }
    __syncthreads();
#pragma unroll
    for (int k = 0; k < 16; ++k) {
      float a[4], bv[4];
#pragma unroll
      for (int i = 0; i < 4; ++i) a[i] = As[k][ty * 4 + i];
#pragma unroll
      for (int j = 0; j < 4; ++j) bv[j] = Bs[k][tx * 4 + j];
#pragma unroll
      for (int i = 0; i < 4; ++i)
#pragma unroll
        for (int j = 0; j < 4; ++j) acc[i][j] += a[i] * bv[j];
    }
    __syncthreads();
  }

#pragma unroll
  for (int i = 0; i < 4; ++i) {
    float4 v = make_float4(acc[i][0] * 0.0625f, acc[i][1] * 0.0625f,
                           acc[i][2] * 0.0625f, acc[i][3] * 0.0625f);
    *(float4*)(out + (size_t)(b0 + ty * 4 + i) * C_CH + d0 + tx * 4) = v;
  }
}

extern "C" void kernel_launch(void* const* d_in, const int* in_sizes, int n_in,
                              void* d_out, int out_size, void* d_ws, size_t ws_size,
                              hipStream_t stream) {
  const float* x  = (const float*)d_in[0];
  const float* U3 = (const float*)d_in[1];
  const float* U2 = (const float*)d_in[2];
  const float* U1 = (const float*)d_in[3];
  const float* w3 = (const float*)d_in[4];
  const float* w2 = (const float*)d_in[5];
  const float* w1 = (const float*)d_in[6];
  const float* Wl = (const float*)d_in[7];

  unsigned int* bfrag = (unsigned int*)((char*)d_ws + OFF_BF_BYTES);
  float*        sT    = (float*)((char*)d_ws + OFF_ST_BYTES);
  float*        out   = (float*)d_out;

  precompute_bfrag<<<dim3(KSTEPS, C_CH / 8), dim3(256), 0, stream>>>(
      U3, U2, U1, w3, w2, w1, bfrag);
  contract_mfma<<<dim3(C_CH / 4, B_NODES / (TILES_PER_WAVE * 16)), dim3(256), 0, stream>>>(
      x, (const short8*)bfrag, sT);
  linear_kernel<<<dim3(B_NODES / 64, C_CH / 64), dim3(256), 0, stream>>>(sT, Wl, out);
}

// Round 10
// 154.383 us; speedup vs baseline: 1.3449x; 1.2544x over previous
//
#include <hip/hip_runtime.h>

// MACE symmetric contraction, B=4096 nodes, C=256 channels, I=16.
//
// Per (b,c):  s[b,c] = sum_p x_p * t[b,p],
//   t[b,p] = sum_{k<256} U3w[c,p,q,i]*x_q*x_i   (k=q*16+i)
//          + sum_q c2[c,p,q]*x_q (k=256+q)  +  c1[c,p] (k=272)
// => K=273 (pad 288=9*32) matmul on mfma_f32_16x16x32_bf16.
// A = coeff[p,k] (regs, static per wave), B = y[k,node] built per tile.
//
// R10: ZERO-ALLOCA contract. R8/R9 showed AMDGPUPromoteAlloca moves private
// float arrays into LDS when no __shared__ is declared (32 KB striped,
// 3.1e7 conflict-cycles), regardless of address-taking. This version has no
// local arrays and no unions at all: named float4/scalar values, selects,
// __builtin_amdgcn_perm + __builtin_bit_cast packing, bf0..bf8 named.
// Wave-autonomous: no LDS, no __syncthreads, 1-tile-ahead reg prefetch.
// NOTE: ~112 us of total dur_us is fixed (harness + precompute + linear).

#define B_NODES 4096
#define C_CH    256
#define K3      23
#define K2      4

#define KSTEPS   9
#define KB_ELEMS (KSTEPS * 64 * 8)   // 4608 bf16 per channel
#define KB_U32   (KB_ELEMS / 2)      // 2304 u32 per channel

#define TILES_PER_WAVE 8             // 128 nodes per wave

typedef short    short8 __attribute__((ext_vector_type(8)));
typedef float    f32x4  __attribute__((ext_vector_type(4)));
typedef unsigned u32x4  __attribute__((ext_vector_type(4)));

// ws layout (bytes): [bfrag: C*4608*2][sT: C*B*4]
static constexpr size_t OFF_BF_BYTES = 0;
static constexpr size_t OFF_ST_BYTES = (size_t)C_CH * KB_ELEMS * 2;

__device__ inline unsigned short f2bf_rne(float f) {
  unsigned u = __builtin_bit_cast(unsigned, f);
  unsigned r = u + 0x7FFFu + ((u >> 16) & 1u);
  return (unsigned short)(r >> 16);
}

#define F2U(f) __builtin_bit_cast(unsigned, (f))
// pack two f32 (truncate-to-bf16 high halves) into one u32: [hi16(YH)|hi16(YL)]
#define PK2(YH, YL) __builtin_amdgcn_perm(F2U(YH), F2U(YL), 0x07060302u)

// ---------------------------------------------------------------------------
// Kernel 1: coeff in fragment order (lane&15 = p, k = s*32+(lane>>4)*8+j).
// grid (9 steps, 32 channel-groups of 8); steps 0..7 stage a 47 KB U3 slice.
// ---------------------------------------------------------------------------
__global__ __launch_bounds__(256) void precompute_bfrag(
    const float* __restrict__ U3, const float* __restrict__ U2,
    const float* __restrict__ U1, const float* __restrict__ w3,
    const float* __restrict__ w2, const float* __restrict__ w1,
    unsigned int* __restrict__ bfrag_u32) {
  const int s  = blockIdx.x;        // K-step 0..8
  const int c0 = blockIdx.y * 8;    // 8 channels per block
  const int t  = threadIdx.x;
  const int lane = t >> 2;          // fragment lane
  const int jj   = (t & 3) * 2;     // 0,2,4,6
  const int p = lane & 15, g = lane >> 4;

  __shared__ float su3[512 * 23];   // rows: p*32 + qb*16 + i

  if (s < 8) {
    for (int l = t; l < 512 * 23; l += 256) {
      const int row = l / 23, col = l - row * 23;
      const int pp = row >> 5, qb = (row >> 4) & 1, ii = row & 15;
      su3[l] = U3[(size_t)((pp * 16 + (2 * s + qb)) * 16 + ii) * K3 + col];
    }
    __syncthreads();

    const int r0 = p * 32 + (g >> 1) * 16 + (g & 1) * 8 + jj;
    float u0[K3], u1[K3];
#pragma unroll
    for (int k3 = 0; k3 < K3; ++k3) {
      u0[k3] = su3[(size_t)r0 * K3 + k3];
      u1[k3] = su3[(size_t)(r0 + 1) * K3 + k3];
    }
#pragma unroll
    for (int ch = 0; ch < 8; ++ch) {
      const int c = c0 + ch;
      float a0 = 0.f, a1 = 0.f;
#pragma unroll
      for (int k3 = 0; k3 < K3; ++k3) {
        const float wv = w3[c * K3 + k3];   // uniform -> scalar load
        a0 += u0[k3] * wv;
        a1 += u1[k3] * wv;
      }
      bfrag_u32[(size_t)c * KB_U32 + s * 256 + t] =
          (unsigned)f2bf_rne(a0) | ((unsigned)f2bf_rne(a1) << 16);
    }
  } else {
    // s == 8: linear rows (x_q), constant row (k==272), pad 0.
#pragma unroll
    for (int ch = 0; ch < 8; ++ch) {
      const int c = c0 + ch;
      float v0 = 0.f, v1 = 0.f;
#pragma unroll
      for (int e = 0; e < 2; ++e) {
        const int k = 256 + g * 8 + jj + e;
        float a = 0.f;
        if (k < 272) {
          const int q = k - 256;
#pragma unroll
          for (int k2 = 0; k2 < K2; ++k2)
            a += U2[(size_t)(p * 16 + q) * K2 + k2] * w2[c * K2 + k2];
        } else if (k == 272) {
          a = U1[p] * w1[c];
        }
        if (e == 0) v0 = a; else v1 = a;
      }
      bfrag_u32[(size_t)c * KB_U32 + s * 256 + t] =
          (unsigned)f2bf_rne(v0) | ((unsigned)f2bf_rne(v1) << 16);
    }
  }
}

// ---------------------------------------------------------------------------
// Kernel 2: wave-autonomous MFMA contraction, zero allocas.
// Block = 256 thr (4 waves); wave w owns channel c0+w; 128 nodes/wave.
// ---------------------------------------------------------------------------

// One quadratic K-step: af rows = xq * xh[0..7], packed bf16.
#define QSTEP(BF, XQ, ACC)                                                     \
  __builtin_amdgcn_mfma_f32_16x16x32_bf16((BF),                                \
      __builtin_bit_cast(short8, (u32x4){                                      \
          PK2((XQ) * xh1, (XQ) * xh0), PK2((XQ) * xh3, (XQ) * xh2),            \
          PK2((XQ) * xh5, (XQ) * xh4), PK2((XQ) * xh7, (XQ) * xh6)}),          \
      (ACC), 0, 0, 0)

#define TILE_BODY(X0, X1, X2, X3, Tc)                                          \
  do {                                                                         \
    const float xh0 = ghi ? (X2).x : (X0).x;                                   \
    const float xh1 = ghi ? (X2).y : (X0).y;                                   \
    const float xh2 = ghi ? (X2).z : (X0).z;                                   \
    const float xh3 = ghi ? (X2).w : (X0).w;                                   \
    const float xh4 = ghi ? (X3).x : (X1).x;                                   \
    const float xh5 = ghi ? (X3).y : (X1).y;                                   \
    const float xh6 = ghi ? (X3).z : (X1).z;                                   \
    const float xh7 = ghi ? (X3).w : (X1).w;                                   \
    const float xq0 = gq ? (X0).y : (X0).x;                                    \
    const float xq1 = gq ? (X0).w : (X0).z;                                    \
    const float xq2 = gq ? (X1).y : (X1).x;                                    \
    const float xq3 = gq ? (X1).w : (X1).z;                                    \
    const float xq4 = gq ? (X2).y : (X2).x;                                    \
    const float xq5 = gq ? (X2).w : (X2).z;                                    \
    const float xq6 = gq ? (X3).y : (X3).x;                                    \
    const float xq7 = gq ? (X3).w : (X3).z;                                    \
    f32x4 acc = (f32x4){0.f, 0.f, 0.f, 0.f};                                   \
    acc = QSTEP(bf0, xq0, acc);                                                \
    acc = QSTEP(bf1, xq1, acc);                                                \
    acc = QSTEP(bf2, xq2, acc);                                                \
    acc = QSTEP(bf3, xq3, acc);                                                \
    acc = QSTEP(bf4, xq4, acc);                                                \
    acc = QSTEP(bf5, xq5, acc);                                                \
    acc = QSTEP(bf6, xq6, acc);                                                \
    acc = QSTEP(bf7, xq7, acc);                                                \
    {                                                                          \
      const float y0 = glin ? xh0 : cst;                                       \
      const float y1 = glin ? xh1 : 0.f;                                       \
      const float y2 = glin ? xh2 : 0.f;                                       \
      const float y3 = glin ? xh3 : 0.f;                                       \
      const float y4 = glin ? xh4 : 0.f;                                       \
      const float y5 = glin ? xh5 : 0.f;                                       \
      const float y6 = glin ? xh6 : 0.f;                                       \
      const float y7 = glin ? xh7 : 0.f;                                       \
      acc = __builtin_amdgcn_mfma_f32_16x16x32_bf16(bf8,                       \
          __builtin_bit_cast(short8, (u32x4){PK2(y1, y0), PK2(y3, y2),         \
                                             PK2(y5, y4), PK2(y7, y6)}),       \
          acc, 0, 0, 0);                                                       \
    }                                                                          \
    const float4 xs = (g & 2) ? ((g & 1) ? (X3) : (X2))                        \
                              : ((g & 1) ? (X1) : (X0));                       \
    float v = acc[0] * xs.x + acc[1] * xs.y + acc[2] * xs.z + acc[3] * xs.w;   \
    v += __shfl_xor(v, 16);                                                    \
    v += __shfl_xor(v, 32);                                                    \
    if (g == 0) sTrow[(Tc) * 16 + n] = v;                                      \
  } while (0)

__global__ __launch_bounds__(256)
__attribute__((amdgpu_waves_per_eu(2, 4)))
void contract_mfma(
    const float* __restrict__ x, const short8* __restrict__ bfragv,
    float* __restrict__ sT) {
  const int c0  = blockIdx.x * 4;                    // channel group (fastest)
  const int nb0 = blockIdx.y * (TILES_PER_WAVE * 16);
  const int t   = threadIdx.x;
  const int w = t >> 6, lane = t & 63, n = lane & 15, g = lane >> 4;
  const int ch = c0 + w;

  // Coeff fragments: 9 coalesced dwordx4 into NAMED registers (36 VGPRs).
  const short8* bp = bfragv + (size_t)ch * (KSTEPS * 64);
  const short8 bf0 = bp[0 * 64 + lane];
  const short8 bf1 = bp[1 * 64 + lane];
  const short8 bf2 = bp[2 * 64 + lane];
  const short8 bf3 = bp[3 * 64 + lane];
  const short8 bf4 = bp[4 * 64 + lane];
  const short8 bf5 = bp[5 * 64 + lane];
  const short8 bf6 = bp[6 * 64 + lane];
  const short8 bf7 = bp[7 * 64 + lane];
  const short8 bf8 = bp[8 * 64 + lane];

  const bool  ghi  = (g & 1) != 0;        // i-half: i = (g&1)*8 + j
  const bool  gq   = ((g >> 1) & 1) != 0; // q = 2s + (g>>1)
  const bool  glin = (g < 2);             // step-8 linear rows live in g<2
  const float cst  = (g == 2) ? 1.0f : 0.0f;  // step-8 constant row
  float* sTrow = sT + (size_t)ch * B_NODES + nb0;

  // x address for lane's node in tile T: row (nb0+T*16+n), this wave's 64B.
  const float* xb = x + (size_t)(nb0 + n) * (C_CH * 16) + (size_t)ch * 16;
  const size_t tstride = (size_t)16 * C_CH * 16;     // 16 nodes

  // Named register double-buffer. No arrays, no address-of.
  float4 a0, a1, a2, a3, b0, b1, b2, b3;
  {
    const float4* p = (const float4*)xb;
    a0 = p[0]; a1 = p[1]; a2 = p[2]; a3 = p[3];
  }

#pragma unroll
  for (int TT = 0; TT < TILES_PER_WAVE / 2; ++TT) {
    {
      const float4* p = (const float4*)(xb + (size_t)(2 * TT + 1) * tstride);
      b0 = p[0]; b1 = p[1]; b2 = p[2]; b3 = p[3];
    }
    TILE_BODY(a0, a1, a2, a3, 2 * TT);
    if (TT + 1 < TILES_PER_WAVE / 2) {
      const float4* p = (const float4*)(xb + (size_t)(2 * TT + 2) * tstride);
      a0 = p[0]; a1 = p[1]; a2 = p[2]; a3 = p[3];
    }
    TILE_BODY(b0, b1, b2, b3, 2 * TT + 1);
  }
}

// ---------------------------------------------------------------------------
// Kernel 3: out[b,d] = (1/16) * sum_c sT[c,b] * W[c,d]  (fp32, 64x64 tiles)
// ---------------------------------------------------------------------------
__global__ __launch_bounds__(256) void linear_kernel(
    const float* __restrict__ sT, const float* __restrict__ W,
    float* __restrict__ out) {
  const int b0 = blockIdx.x * 64;
  const int d0 = blockIdx.y * 64;
  const int t  = threadIdx.x;
  const int tx = t & 15;
  const int ty = t >> 4;

  __shared__ float As[16][64];
  __shared__ float Bs[16][64];
  float acc[4][4] = {};

  for (int k0 = 0; k0 < C_CH; k0 += 16) {
    const int kk  = t >> 6;
    const int col = t & 63;
#pragma unroll
    for (int r = 0; r < 4; ++r) {
      As[kk + r * 4][col] = sT[(size_t)(k0 + kk + r * 4) * B_NODES + b0 + col];
      Bs[kk + r * 4][col] = W[(size_t)(k0 + kk + r * 4) * C_CH + d0 + col];
    }
    __syncthreads();
#pragma unroll
    for (int k = 0; k < 16; ++k) {
      float a[4], bv[4];
#pragma unroll
      for (int i = 0; i < 4; ++i) a[i] = As[k][ty * 4 + i];
#pragma unroll
      for (int j = 0; j < 4; ++j) bv[j] = Bs[k][tx * 4 + j];
#pragma unroll
      for (int i = 0; i < 4; ++i)
#pragma unroll
        for (int j = 0; j < 4; ++j) acc[i][j] += a[i] * bv[j];
    }
    __syncthreads();
  }

#pragma unroll
  for (int i = 0; i < 4; ++i) {
    float4 v = make_float4(acc[i][0] * 0.0625f, acc[i][1] * 0.0625f,
                           acc[i][2] * 0.0625f, acc[i][3] * 0.0625f);
    *(float4*)(out + (size_t)(b0 + ty * 4 + i) * C_CH + d0 + tx * 4) = v;
  }
}

extern "C" void kernel_launch(void* const* d_in, const int* in_sizes, int n_in,
                              void* d_out, int out_size, void* d_ws, size_t ws_size,
                              hipStream_t stream) {
  const float* x  = (const float*)d_in[0];
  const float* U3 = (const float*)d_in[1];
  const float* U2 = (const float*)d_in[2];
  const float* U1 = (const float*)d_in[3];
  const float* w3 = (const float*)d_in[4];
  const float* w2 = (const float*)d_in[5];
  const float* w1 = (const float*)d_in[6];
  const float* Wl = (const float*)d_in[7];

  unsigned int* bfrag = (unsigned int*)((char*)d_ws + OFF_BF_BYTES);
  float*        sT    = (float*)((char*)d_ws + OFF_ST_BYTES);
  float*        out   = (float*)d_out;

  precompute_bfrag<<<dim3(KSTEPS, C_CH / 8), dim3(256), 0, stream>>>(
      U3, U2, U1, w3, w2, w1, bfrag);
  contract_mfma<<<dim3(C_CH / 4, B_NODES / (TILES_PER_WAVE * 16)), dim3(256), 0, stream>>>(
      x, (const short8*)bfrag, sT);
  linear_kernel<<<dim3(B_NODES / 64, C_CH / 64), dim3(256), 0, stream>>>(sT, Wl, out);
}